// Round 24
// baseline (107.988 us; speedup 1.0000x reference)
//
#include <hip/hip_runtime.h>

// Problem constants
#define BB 2
#define SQ 2048
#define SK 2048
#define DD 1024
#define HH 16
#define HS 64
#define SCALE 0.125f
#define LOG2E 1.4426950408889634f

typedef __bf16 bf16x8 __attribute__((ext_vector_type(8)));
typedef float f32x4 __attribute__((ext_vector_type(4)));
typedef unsigned int uint;

// Fast hardware exp2 (exp2f without -ffast-math lowers to the ~20-instr OCML path)
#if defined(__has_builtin)
#if __has_builtin(__builtin_amdgcn_exp2f)
#define FEXP2(x) __builtin_amdgcn_exp2f(x)
#endif
#endif
#ifndef FEXP2
extern "C" __device__ float __ocml_native_exp2_f32(float);
#define FEXP2(x) __ocml_native_exp2_f32(x)
#endif

__device__ __forceinline__ void gload_lds16(const __bf16* g, __bf16* l) {
    __builtin_amdgcn_global_load_lds((const __attribute__((address_space(1))) uint*)(g),
                                     (__attribute__((address_space(3))) uint*)(l), 16, 0, 0);
}

// ------------- cast+transpose weights [K][N] -> bf16 [N][K], B-read swizzle baked in -------------
__global__ void wtrans(const float* __restrict__ W0, const float* __restrict__ W1,
                       const float* __restrict__ W2, const float* __restrict__ W3,
                       __bf16* __restrict__ Wt) {
    __shared__ __bf16 tile[32][33];
    const float* W = blockIdx.z == 0 ? W0 : blockIdx.z == 1 ? W1 : blockIdx.z == 2 ? W2 : W3;
    __bf16* out = Wt + (size_t)blockIdx.z * DD * DD;
    int tx = threadIdx.x, ty = threadIdx.y;     // (32, 8)
    int k0 = blockIdx.y * 32, n0 = blockIdx.x * 32;
#pragma unroll
    for (int j = 0; j < 4; ++j)
        tile[ty + j * 8][tx] = (__bf16)W[(size_t)(k0 + ty + j * 8) * DD + n0 + tx];
    __syncthreads();
#pragma unroll
    for (int j = 0; j < 4; ++j) {
        int n = n0 + ty + j * 8;
        int k = k0 + tx;
        int kswz = (k & ~63) | ((((k >> 3) ^ n) & 7) << 3) | (k & 7);
        out[(size_t)n * DD + kswz] = tile[tx][ty + j * 8];
    }
}

// ------------- unified QKV projection GEMM: 128-row A tile, B via double-buffered gload_lds -------------
// r18 + one change: B staging moved to global_load_lds (unsinkable prefetch, issued a FULL
// step before its consuming barrier) into a double-buffered Bs; A stays reg-staged fused-cast.
// Loop: bar1 -> A_WRITE (4 ds_writes; vmcnt waits only A's 8 loads) -> bar2 (drains B(t)
// gloads issued one iteration earlier) -> issue A_LOAD(t+1) + B_GLOAD(t+1, other buf) -> MFMA.
// Wave grid 2x2, wave-tile 64x64, acc[4][4] = 32 MFMA/wave/step. LDS 48 KB -> 3 blocks/CU.
__global__ __launch_bounds__(256, 3) void gemm_qkv(
        const float* __restrict__ Ain, const float* __restrict__ Actx,
        const __bf16* __restrict__ Wt,
        const float* __restrict__ bq, const float* __restrict__ bk, const float* __restrict__ bv,
        __bf16* __restrict__ Qb, __bf16* __restrict__ Kb, __bf16* __restrict__ Vtb,
        float qscale) {
    __shared__ __bf16 As[128 * 64];       // 16 KB (single buffer)
    __shared__ __bf16 Bs[2 * 128 * 64];   // 32 KB (double-buffered, gload_lds)
    int t = threadIdx.x, w = t >> 6, l = t & 63;
    int lm = l & 15, lk = l >> 4;
    int wr = w >> 1, wc = w & 1;
    // T1 XCD swizzle over 768 wgs (grid 16x48): each XCD gets 96 contiguous nf
    int flat = blockIdx.x + 16 * blockIdx.y;
    int nf = (flat & 7) * 96 + (flat >> 3);
    bool isQ = nf < 256;
    int bc, br;
    if (isQ) { bc = nf & 7; br = nf >> 3; }                  // 8 col-tiles(128) x 32 row-tiles(128)
    else     { int f = nf - 256; bc = f & 15; br = f >> 4; } // 16 col-tiles(64+64) x 32 row-tiles

    // A staging: thread covers (rows rA + 32j, bf16-chunk cA); 2 float4 fp32 per chunk
    int rA = t >> 3, cA = t & 7;
    const float* Afp = isQ ? Ain : Actx;
    const float* agb = Afp + (size_t)(br * 128 + rA) * 1024 + cA * 8;
    __bf16* aw = &As[rA * 64 + ((cA ^ (rA & 7)) * 8)];   // (rA+32j)&7 == rA&7

    // B staging (gload_lds): rows rA + 32j, chunk cA; pre-swizzled Wt -> linear source+dest
    const __bf16 *bg0, *bg1, *bg2, *bg3;
    if (isQ) {
        const __bf16* Wq_ = Wt;
        bg0 = Wq_ + (size_t)(bc * 128 + rA)      * 1024 + cA * 8;
        bg1 = Wq_ + (size_t)(bc * 128 + rA + 32) * 1024 + cA * 8;
        bg2 = Wq_ + (size_t)(bc * 128 + rA + 64) * 1024 + cA * 8;
        bg3 = Wq_ + (size_t)(bc * 128 + rA + 96) * 1024 + cA * 8;
    } else {
        const __bf16* Wk_ = Wt + (size_t)DD * DD;
        const __bf16* Wv_ = Wt + (size_t)2 * DD * DD;
        bg0 = Wk_ + (size_t)(bc * 64 + rA)      * 1024 + cA * 8;
        bg1 = Wk_ + (size_t)(bc * 64 + rA + 32) * 1024 + cA * 8;
        bg2 = Wv_ + (size_t)(bc * 64 + rA)      * 1024 + cA * 8;
        bg3 = Wv_ + (size_t)(bc * 64 + rA + 32) * 1024 + cA * 8;
    }
    __bf16* bdst = &Bs[rA * 64 + cA * 8];

    int brow[4];
#pragma unroll
    for (int n = 0; n < 4; ++n)
        brow[n] = isQ ? (wc * 64 + n * 16 + lm)
                      : ((n >> 1) * 64 + wc * 32 + (n & 1) * 16 + lm);

    // NAMED staging regs: A only (8 float4)
    float4 a0l, a0h, a1l, a1h, a2l, a2h, a3l, a3h;
#define A_LOAD()                                                                      \
    a0l = *(const float4*)(agb);              a0h = *(const float4*)(agb + 4);        \
    a1l = *(const float4*)(agb + 32768);      a1h = *(const float4*)(agb + 32772);    \
    a2l = *(const float4*)(agb + 65536);      a2h = *(const float4*)(agb + 65540);    \
    a3l = *(const float4*)(agb + 98304);      a3h = *(const float4*)(agb + 98308);    \
    agb += 64;
#define CVT8(LO, HI) bf16x8{(__bf16)LO.x, (__bf16)LO.y, (__bf16)LO.z, (__bf16)LO.w,   \
                            (__bf16)HI.x, (__bf16)HI.y, (__bf16)HI.z, (__bf16)HI.w}
#define A_WRITE()                                                                     \
    {                                                                                 \
        *(bf16x8*)(aw)        = CVT8(a0l, a0h);                                       \
        *(bf16x8*)(aw + 2048) = CVT8(a1l, a1h);                                       \
        *(bf16x8*)(aw + 4096) = CVT8(a2l, a2h);                                       \
        *(bf16x8*)(aw + 6144) = CVT8(a3l, a3h);                                       \
    }
#define B_STAGE(BUF, KT)                                                              \
    gload_lds16(bg0 + (KT), bdst + (BUF) * 8192);                                     \
    gload_lds16(bg1 + (KT), bdst + (BUF) * 8192 + 2048);                              \
    gload_lds16(bg2 + (KT), bdst + (BUF) * 8192 + 4096);                              \
    gload_lds16(bg3 + (KT), bdst + (BUF) * 8192 + 6144);

    f32x4 acc[4][4] = {};
    A_LOAD();
    B_STAGE(0, 0);
    for (int ts = 0; ts < 16; ++ts) {
        int bufB = ts & 1;
        __syncthreads();                       // bar1: previous step's As reads done
        A_WRITE();                             // waits only A's 8 loads; 4 ds_writes
        __syncthreads();                       // bar2: drains A writes + B(ts) gloads
        if (ts + 1 < 16) {
            A_LOAD();                          // A regs for ts+1 (hide under MFMA)
            B_STAGE(bufB ^ 1, (ts + 1) * 64);  // B(ts+1) in flight a FULL step early
        }
#pragma unroll
        for (int kk = 0; kk < 2; ++kk) {
            int ch = kk * 4 + lk;
            bf16x8 af[4], bf[4];
#pragma unroll
            for (int m = 0; m < 4; ++m)
                af[m] = *(const bf16x8*)&As[(wr * 64 + m * 16 + lm) * 64 + ((ch ^ (lm & 7)) * 8)];
#pragma unroll
            for (int n = 0; n < 4; ++n)
                bf[n] = *(const bf16x8*)&Bs[bufB * 8192 + brow[n] * 64 + ((ch ^ (lm & 7)) * 8)];
#pragma unroll
            for (int m = 0; m < 4; ++m)
#pragma unroll
                for (int n = 0; n < 4; ++n)
                    acc[m][n] = __builtin_amdgcn_mfma_f32_16x16x32_bf16(af[m], bf[n], acc[m][n], 0, 0, 0);
        }
    }
#undef A_LOAD
#undef A_WRITE
#undef B_STAGE
#undef CVT8

    if (isQ) {
#pragma unroll
        for (int m = 0; m < 4; ++m)
#pragma unroll
            for (int n = 0; n < 4; ++n) {
                int col = bc * 128 + wc * 64 + n * 16 + lm;
                float bb = bq[col];
#pragma unroll
                for (int r = 0; r < 4; ++r) {
                    int row = br * 128 + wr * 64 + m * 16 + lk * 4 + r;
                    Qb[(size_t)row * 1024 + col] = (__bf16)((acc[m][n][r] + bb) * qscale);
                }
            }
    } else {
#pragma unroll
        for (int m = 0; m < 4; ++m)
#pragma unroll
            for (int n = 0; n < 4; ++n) {
                int col = bc * 64 + wc * 32 + (n & 1) * 16 + lm;
                if (n < 2) {
                    float bb = bk[col];
#pragma unroll
                    for (int r = 0; r < 4; ++r) {
                        int row = br * 128 + wr * 64 + m * 16 + lk * 4 + r;
                        Kb[(size_t)row * 1024 + col] = (__bf16)(acc[m][n][r] + bb);
                    }
                } else {
                    // Vt value for key-pos sk stored at sigma-permuted position:
                    // within 64-block: p = o5<<5 | o3<<4 | o2<<3 | o4<<2 (quad base)
                    float bb = bv[col];
                    int row = br * 128 + wr * 64 + m * 16 + lk * 4;   // sk quad base
                    int b_ = row >> 11, sk = row & 2047;
                    int skb = sk & ~63, o = sk & 63;
                    int p0 = (o & 32) | (((o >> 3) & 1) << 4) | (((o >> 2) & 1) << 3) | (((o >> 4) & 1) << 2);
                    int h_ = col >> 6, d_ = col & 63;
                    union { ushort4 u; __bf16 hh[4]; } pk;
#pragma unroll
                    for (int r = 0; r < 4; ++r) pk.hh[r] = (__bf16)(acc[m][n][r] + bb);
                    *(ushort4*)(Vtb + ((size_t)((b_ * 16 + h_) * 64 + d_) * 2048 + skb + p0)) = pk.u;
                }
            }
    }
}

// ------------- output GEMM: 64x128 tile, float out, T1 XCD swizzle (r14 verbatim) -------------
__global__ __launch_bounds__(256) void gemm_out64(const __bf16* __restrict__ A, const __bf16* __restrict__ Bt,
                                                  const float* __restrict__ bias, float* __restrict__ C) {
    __shared__ __bf16 As[64][64];
    __shared__ __bf16 Bs[128][64];
    int t = threadIdx.x;
    int w = t >> 6, l = t & 63;
    int lm = l & 15, lk = l >> 4;
    int flat = blockIdx.x + 8 * blockIdx.y;
    int nf = (flat & 7) * 64 + (flat >> 3);
    int bc = nf & 7, br = nf >> 3;
    int srow = (l >> 3), scol = (l & 7) * 8;
    f32x4 acc[4][2] = {};
    for (int kt = 0; kt < 1024; kt += 64) {
        __syncthreads();
#pragma unroll
        for (int j = 0; j < 2; ++j) {
            int r0 = (j * 4 + w) * 8;
            gload_lds16(&A[(size_t)(br * 64 + r0 + srow) * 1024 + kt + scol], &As[r0][0]);
        }
#pragma unroll
        for (int j = 0; j < 4; ++j) {
            int r0 = (j * 4 + w) * 8;
            gload_lds16(&Bt[(size_t)(bc * 128 + r0 + srow) * 1024 + kt + scol], &Bs[r0][0]);
        }
        __syncthreads();
#pragma unroll
        for (int kk = 0; kk < 64; kk += 32) {
            int ch = ((kk >> 3) + lk);
            bf16x8 af[4], bf[2];
#pragma unroll
            for (int m = 0; m < 4; ++m) af[m] = *(const bf16x8*)&As[m * 16 + lm][kk + lk * 8];
#pragma unroll
            for (int n = 0; n < 2; ++n)
                bf[n] = *(const bf16x8*)&Bs[w * 32 + n * 16 + lm][(ch ^ (lm & 7)) * 8];
#pragma unroll
            for (int m = 0; m < 4; ++m)
#pragma unroll
                for (int n = 0; n < 2; ++n)
                    acc[m][n] = __builtin_amdgcn_mfma_f32_16x16x32_bf16(af[m], bf[n], acc[m][n], 0, 0, 0);
        }
    }
#pragma unroll
    for (int m = 0; m < 4; ++m)
#pragma unroll
        for (int n = 0; n < 2; ++n) {
            int col = bc * 128 + w * 32 + n * 16 + lm;
            float bv = bias[col];
#pragma unroll
            for (int r = 0; r < 4; ++r) {
                int row = br * 64 + m * 16 + lk * 4 + r;
                C[(size_t)row * 1024 + col] = acc[m][n][r] + bv;
            }
        }
}

// ------------- flash attention (r14/r18 2-buffer version, verbatim) -------------
__global__ __launch_bounds__(512) void flash_attn(const __bf16* __restrict__ Q,
                                                  const __bf16* __restrict__ Kb,
                                                  const __bf16* __restrict__ Vt,
                                                  __bf16* __restrict__ O) {
    __shared__ __bf16 Ks[2][64 * 64];
    __shared__ __bf16 Vs[2][64 * 64];
    int t = threadIdx.x, w = t >> 6, l = t & 63;
    int lm = l & 15, lk = l >> 4;
    int flat = blockIdx.x + 16 * blockIdx.y;
    int nf = (flat & 7) * 64 + (flat >> 3);
    int bh = nf >> 4, b = bh >> 4, h = bh & 15;
    int q0 = (nf & 15) * 128;

    bf16x8 qf[2];
#pragma unroll
    for (int kk = 0; kk < 2; ++kk)
        qf[kk] = *(const bf16x8*)&Q[(size_t)(b * SQ + q0 + w * 16 + lm) * DD + h * HS + kk * 32 + lk * 8];

    int r0 = t >> 3, c8 = t & 7;
    int chs = c8 ^ (r0 & 7);
    __bf16* ksl0 = &Ks[0][r0 * 64 + chs * 8];
    __bf16* vsl0 = &Vs[0][r0 * 64 + chs * 8];

    const __bf16* kp0 = Kb + (size_t)b * SK * DD + h * HS + (size_t)r0 * DD + c8 * 8;
    const __bf16* vp0 = Vt + (size_t)bh * HS * SK + (size_t)r0 * SK + c8 * 8;

    int o0 = lm * 64 + ((lk ^ (lm & 7)) * 8);
    int o1 = lm * 64 + (((4 + lk) ^ (lm & 7)) * 8);

    float4 kr0, vr0;
#define FA_LOAD()                                                                \
    kr0 = *(const float4*)kp0; vr0 = *(const float4*)vp0;                        \
    kp0 += (size_t)64 * DD; vp0 += 64;
#define FA_WRITE(BUF)                                                            \
    *(float4*)(ksl0 + (BUF) * 4096) = kr0;                                       \
    *(float4*)(vsl0 + (BUF) * 4096) = vr0;

    FA_LOAD();
    FA_WRITE(0);
    __syncthreads();

    bf16x8 ones;
#pragma unroll
    for (int j = 0; j < 8; ++j) ones[j] = (__bf16)1.0f;

    f32x4 o[4] = {};
    f32x4 o_s = {};

    for (int it = 0; it < 32; ++it) {
        int buf = it & 1;
        if (it + 1 < 32) { FA_LOAD(); }

        const __bf16* KsB = &Ks[buf][0];
        const __bf16* VsB = &Vs[buf][0];

        f32x4 st[4] = {};
        __builtin_amdgcn_s_setprio(1);
#pragma unroll
        for (int kk = 0; kk < 2; ++kk) {
#pragma unroll
            for (int n = 0; n < 4; ++n) {
                bf16x8 kf = *(const bf16x8*)&KsB[(kk ? o1 : o0) + n * 1024];
                st[n] = __builtin_amdgcn_mfma_f32_16x16x32_bf16(kf, qf[kk], st[n], 0, 0, 0);
            }
        }
        __builtin_amdgcn_s_setprio(0);

#pragma unroll
        for (int kk = 0; kk < 2; ++kk) {
            bf16x8 pa;
#pragma unroll
            for (int j = 0; j < 8; ++j)
                pa[j] = (__bf16)FEXP2(st[2 * kk + (j >> 2)][j & 3]);
            __builtin_amdgcn_s_setprio(1);
            o_s = __builtin_amdgcn_mfma_f32_16x16x32_bf16(pa, ones, o_s, 0, 0, 0);
#pragma unroll
            for (int dn = 0; dn < 4; ++dn) {
                bf16x8 vf = *(const bf16x8*)&VsB[(kk ? o1 : o0) + dn * 1024];
                o[dn] = __builtin_amdgcn_mfma_f32_16x16x32_bf16(pa, vf, o[dn], 0, 0, 0);
            }
            __builtin_amdgcn_s_setprio(0);
        }

        if (it + 1 < 32) { FA_WRITE(buf ^ 1); }
        __syncthreads();
    }

    f32x4 inv;
#pragma unroll
    for (int r = 0; r < 4; ++r) inv[r] = 1.f / o_s[r];
#pragma unroll
    for (int dn = 0; dn < 4; ++dn)
#pragma unroll
        for (int r = 0; r < 4; ++r) {
            int row = q0 + w * 16 + lk * 4 + r;
            int col = h * HS + dn * 16 + lm;
            O[(size_t)(b * SQ + row) * DD + col] = (__bf16)(o[dn][r] * inv[r]);
        }
}

extern "C" void kernel_launch(void* const* d_in, const int* in_sizes, int n_in,
                              void* d_out, int out_size, void* d_ws, size_t ws_size,
                              hipStream_t stream) {
    const float* inputs  = (const float*)d_in[0];
    const float* context = (const float*)d_in[1];
    const float* Wq = (const float*)d_in[2];
    const float* bq = (const float*)d_in[3];
    const float* Wk = (const float*)d_in[4];
    const float* bk = (const float*)d_in[5];
    const float* Wv = (const float*)d_in[6];
    const float* bv = (const float*)d_in[7];
    const float* Wo = (const float*)d_in[8];
    const float* bo = (const float*)d_in[9];
    float* out = (float*)d_out;

    char* ws = (char*)d_ws;
    const size_t SEG = (size_t)4096 * 1024 * sizeof(__bf16);  // 8 MB
    __bf16* attb = (__bf16*)(ws + 0 * SEG);   // attention output (bf16)
    __bf16* Wt   = (__bf16*)(ws + 2 * SEG);   // 4 x 1024x1024 bf16 (B-swizzled layout)
    __bf16* Qb   = (__bf16*)(ws + 3 * SEG);
    __bf16* Kbuf = (__bf16*)(ws + 4 * SEG);
    __bf16* Vtb  = (__bf16*)(ws + 5 * SEG);   // V transposed + sigma-permuted by gemm_qkv

    wtrans<<<dim3(32, 32, 4), dim3(32, 8), 0, stream>>>(Wq, Wk, Wv, Wo, Wt);

    gemm_qkv<<<dim3(16, 48), 256, 0, stream>>>(inputs, context, Wt, bq, bk, bv,
                                               Qb, Kbuf, Vtb, SCALE * LOG2E);

    flash_attn<<<dim3(16, 32), 512, 0, stream>>>(Qb, Kbuf, Vtb, attb);

    gemm_out64<<<dim3(8, 64), 256, 0, stream>>>(attb, Wt + (size_t)3 * DD * DD, bo, out);
}

// Round 25
// 105.141 us; speedup vs baseline: 1.0271x; 1.0271x over previous
//
#include <hip/hip_runtime.h>

// Problem constants
#define BB 2
#define SQ 2048
#define SK 2048
#define DD 1024
#define HH 16
#define HS 64
#define SCALE 0.125f
#define LOG2E 1.4426950408889634f

typedef __bf16 bf16x8 __attribute__((ext_vector_type(8)));
typedef float f32x4 __attribute__((ext_vector_type(4)));
typedef unsigned int uint;

// Fast hardware exp2 (exp2f without -ffast-math lowers to the ~20-instr OCML path)
#if defined(__has_builtin)
#if __has_builtin(__builtin_amdgcn_exp2f)
#define FEXP2(x) __builtin_amdgcn_exp2f(x)
#endif
#endif
#ifndef FEXP2
extern "C" __device__ float __ocml_native_exp2_f32(float);
#define FEXP2(x) __ocml_native_exp2_f32(x)
#endif

__device__ __forceinline__ void gload_lds16(const __bf16* g, __bf16* l) {
    __builtin_amdgcn_global_load_lds((const __attribute__((address_space(1))) uint*)(g),
                                     (__attribute__((address_space(3))) uint*)(l), 16, 0, 0);
}

// ------------- cast+transpose weights [K][N] -> bf16 [N][K], B-read swizzle baked in -------------
__global__ void wtrans(const float* __restrict__ W0, const float* __restrict__ W1,
                       const float* __restrict__ W2, const float* __restrict__ W3,
                       __bf16* __restrict__ Wt) {
    __shared__ __bf16 tile[32][33];
    const float* W = blockIdx.z == 0 ? W0 : blockIdx.z == 1 ? W1 : blockIdx.z == 2 ? W2 : W3;
    __bf16* out = Wt + (size_t)blockIdx.z * DD * DD;
    int tx = threadIdx.x, ty = threadIdx.y;     // (32, 8)
    int k0 = blockIdx.y * 32, n0 = blockIdx.x * 32;
#pragma unroll
    for (int j = 0; j < 4; ++j)
        tile[ty + j * 8][tx] = (__bf16)W[(size_t)(k0 + ty + j * 8) * DD + n0 + tx];
    __syncthreads();
#pragma unroll
    for (int j = 0; j < 4; ++j) {
        int n = n0 + ty + j * 8;
        int k = k0 + tx;
        int kswz = (k & ~63) | ((((k >> 3) ^ n) & 7) << 3) | (k & 7);
        out[(size_t)n * DD + kswz] = tile[tx][ty + j * 8];
    }
}

// ------------- unified QKV projection GEMM: 128-row A tile, 32 MFMA/wave/step (r18, best measured) -------------
// A: fp32 reg-staged fused cast (8 named float4), XOR-chunk-swizzled LDS write, swizzled read.
// B: reg-staged from pre-swizzled Wt. Loop: barrier -> G_WRITE -> barrier -> G_LOAD(t+1) -> MFMA.
// Wave grid 2x2, wave-tile 64x64, acc[4][4]. Q-blocks (nf<256): A=inputs vs 128 cols Wq.
// KV-blocks: A=context vs 64 Wk + 64 Wv cols (one A staging feeds BOTH outputs).
__global__ __launch_bounds__(256, 3) void gemm_qkv(
        const float* __restrict__ Ain, const float* __restrict__ Actx,
        const __bf16* __restrict__ Wt,
        const float* __restrict__ bq, const float* __restrict__ bk, const float* __restrict__ bv,
        __bf16* __restrict__ Qb, __bf16* __restrict__ Kb, __bf16* __restrict__ Vtb,
        float qscale) {
    __shared__ __bf16 As[128 * 64];   // 16 KB
    __shared__ __bf16 Bs[128 * 64];   // 16 KB
    int t = threadIdx.x, w = t >> 6, l = t & 63;
    int lm = l & 15, lk = l >> 4;
    int wr = w >> 1, wc = w & 1;
    // T1 XCD swizzle over 768 wgs (grid 16x48): each XCD gets 96 contiguous nf
    int flat = blockIdx.x + 16 * blockIdx.y;
    int nf = (flat & 7) * 96 + (flat >> 3);
    bool isQ = nf < 256;
    int bc, br;
    if (isQ) { bc = nf & 7; br = nf >> 3; }                  // 8 col-tiles(128) x 32 row-tiles(128)
    else     { int f = nf - 256; bc = f & 15; br = f >> 4; } // 16 col-tiles(64+64) x 32 row-tiles

    // A staging: thread covers (rows rA + 32j, bf16-chunk cA); 2 float4 fp32 per chunk
    int rA = t >> 3, cA = t & 7;
    const float* Afp = isQ ? Ain : Actx;
    const float* agb = Afp + (size_t)(br * 128 + rA) * 1024 + cA * 8;
    __bf16* aw = &As[rA * 64 + ((cA ^ (rA & 7)) * 8)];   // (rA+32j)&7 == rA&7

    // B staging: rows rA + 32j, chunk cA (source pre-swizzled -> linear write)
    const __bf16 *bg0, *bg1, *bg2, *bg3;
    if (isQ) {
        const __bf16* Wq_ = Wt;
        bg0 = Wq_ + (size_t)(bc * 128 + rA)      * 1024 + cA * 8;
        bg1 = Wq_ + (size_t)(bc * 128 + rA + 32) * 1024 + cA * 8;
        bg2 = Wq_ + (size_t)(bc * 128 + rA + 64) * 1024 + cA * 8;
        bg3 = Wq_ + (size_t)(bc * 128 + rA + 96) * 1024 + cA * 8;
    } else {
        const __bf16* Wk_ = Wt + (size_t)DD * DD;
        const __bf16* Wv_ = Wt + (size_t)2 * DD * DD;
        bg0 = Wk_ + (size_t)(bc * 64 + rA)      * 1024 + cA * 8;
        bg1 = Wk_ + (size_t)(bc * 64 + rA + 32) * 1024 + cA * 8;
        bg2 = Wv_ + (size_t)(bc * 64 + rA)      * 1024 + cA * 8;
        bg3 = Wv_ + (size_t)(bc * 64 + rA + 32) * 1024 + cA * 8;
    }
    __bf16* bw = &Bs[rA * 64 + cA * 8];

    int brow[4];
#pragma unroll
    for (int n = 0; n < 4; ++n)
        brow[n] = isQ ? (wc * 64 + n * 16 + lm)
                      : ((n >> 1) * 64 + wc * 32 + (n & 1) * 16 + lm);

    // NAMED staging regs: A = 8 float4 (4 row-strides x lo/hi), B = 4 float4
    float4 a0l, a0h, a1l, a1h, a2l, a2h, a3l, a3h, xb0, xb1, xb2, xb3;
#define G_LOAD()                                                                      \
    a0l = *(const float4*)(agb);              a0h = *(const float4*)(agb + 4);        \
    a1l = *(const float4*)(agb + 32768);      a1h = *(const float4*)(agb + 32772);    \
    a2l = *(const float4*)(agb + 65536);      a2h = *(const float4*)(agb + 65540);    \
    a3l = *(const float4*)(agb + 98304);      a3h = *(const float4*)(agb + 98308);    \
    xb0 = *(const float4*)bg0; xb1 = *(const float4*)bg1;                             \
    xb2 = *(const float4*)bg2; xb3 = *(const float4*)bg3;                             \
    agb += 64; bg0 += 64; bg1 += 64; bg2 += 64; bg3 += 64;
#define CVT8(LO, HI) bf16x8{(__bf16)LO.x, (__bf16)LO.y, (__bf16)LO.z, (__bf16)LO.w,   \
                            (__bf16)HI.x, (__bf16)HI.y, (__bf16)HI.z, (__bf16)HI.w}
#define G_WRITE()                                                                     \
    {                                                                                 \
        *(bf16x8*)(aw)        = CVT8(a0l, a0h);                                       \
        *(bf16x8*)(aw + 2048) = CVT8(a1l, a1h);                                       \
        *(bf16x8*)(aw + 4096) = CVT8(a2l, a2h);                                       \
        *(bf16x8*)(aw + 6144) = CVT8(a3l, a3h);                                       \
        *(float4*)(bw)        = xb0;                                                  \
        *(float4*)(bw + 2048) = xb1;                                                  \
        *(float4*)(bw + 4096) = xb2;                                                  \
        *(float4*)(bw + 6144) = xb3;                                                  \
    }

    f32x4 acc[4][4] = {};
    G_LOAD();
    for (int ts = 0; ts < 16; ++ts) {
        __syncthreads();                       // previous step's LDS reads done
        G_WRITE();                             // land tiles (fp32->bf16 cvt for A)
        __syncthreads();                       // writes visible
        if (ts + 1 < 16) { G_LOAD(); }         // next tile's loads hide under MFMA
#pragma unroll
        for (int kk = 0; kk < 2; ++kk) {
            int ch = kk * 4 + lk;
            bf16x8 af[4], bf[4];
#pragma unroll
            for (int m = 0; m < 4; ++m)
                af[m] = *(const bf16x8*)&As[(wr * 64 + m * 16 + lm) * 64 + ((ch ^ (lm & 7)) * 8)];
#pragma unroll
            for (int n = 0; n < 4; ++n)
                bf[n] = *(const bf16x8*)&Bs[brow[n] * 64 + ((ch ^ (lm & 7)) * 8)];
#pragma unroll
            for (int m = 0; m < 4; ++m)
#pragma unroll
                for (int n = 0; n < 4; ++n)
                    acc[m][n] = __builtin_amdgcn_mfma_f32_16x16x32_bf16(af[m], bf[n], acc[m][n], 0, 0, 0);
        }
    }
#undef G_LOAD
#undef G_WRITE
#undef CVT8

    if (isQ) {
#pragma unroll
        for (int m = 0; m < 4; ++m)
#pragma unroll
            for (int n = 0; n < 4; ++n) {
                int col = bc * 128 + wc * 64 + n * 16 + lm;
                float bb = bq[col];
#pragma unroll
                for (int r = 0; r < 4; ++r) {
                    int row = br * 128 + wr * 64 + m * 16 + lk * 4 + r;
                    Qb[(size_t)row * 1024 + col] = (__bf16)((acc[m][n][r] + bb) * qscale);
                }
            }
    } else {
#pragma unroll
        for (int m = 0; m < 4; ++m)
#pragma unroll
            for (int n = 0; n < 4; ++n) {
                int col = bc * 64 + wc * 32 + (n & 1) * 16 + lm;
                if (n < 2) {
                    float bb = bk[col];
#pragma unroll
                    for (int r = 0; r < 4; ++r) {
                        int row = br * 128 + wr * 64 + m * 16 + lk * 4 + r;
                        Kb[(size_t)row * 1024 + col] = (__bf16)(acc[m][n][r] + bb);
                    }
                } else {
                    // Vt value for key-pos sk stored at sigma-permuted position:
                    // within 64-block: p = o5<<5 | o3<<4 | o2<<3 | o4<<2 (quad base)
                    float bb = bv[col];
                    int row = br * 128 + wr * 64 + m * 16 + lk * 4;   // sk quad base
                    int b_ = row >> 11, sk = row & 2047;
                    int skb = sk & ~63, o = sk & 63;
                    int p0 = (o & 32) | (((o >> 3) & 1) << 4) | (((o >> 2) & 1) << 3) | (((o >> 4) & 1) << 2);
                    int h_ = col >> 6, d_ = col & 63;
                    union { ushort4 u; __bf16 hh[4]; } pk;
#pragma unroll
                    for (int r = 0; r < 4; ++r) pk.hh[r] = (__bf16)(acc[m][n][r] + bb);
                    *(ushort4*)(Vtb + ((size_t)((b_ * 16 + h_) * 64 + d_) * 2048 + skb + p0)) = pk.u;
                }
            }
    }
}

// ------------- output GEMM: 64x128 tile, float out, T1 XCD swizzle (r14 verbatim) -------------
__global__ __launch_bounds__(256) void gemm_out64(const __bf16* __restrict__ A, const __bf16* __restrict__ Bt,
                                                  const float* __restrict__ bias, float* __restrict__ C) {
    __shared__ __bf16 As[64][64];
    __shared__ __bf16 Bs[128][64];
    int t = threadIdx.x;
    int w = t >> 6, l = t & 63;
    int lm = l & 15, lk = l >> 4;
    int flat = blockIdx.x + 8 * blockIdx.y;
    int nf = (flat & 7) * 64 + (flat >> 3);
    int bc = nf & 7, br = nf >> 3;
    int srow = (l >> 3), scol = (l & 7) * 8;
    f32x4 acc[4][2] = {};
    for (int kt = 0; kt < 1024; kt += 64) {
        __syncthreads();
#pragma unroll
        for (int j = 0; j < 2; ++j) {
            int r0 = (j * 4 + w) * 8;
            gload_lds16(&A[(size_t)(br * 64 + r0 + srow) * 1024 + kt + scol], &As[r0][0]);
        }
#pragma unroll
        for (int j = 0; j < 4; ++j) {
            int r0 = (j * 4 + w) * 8;
            gload_lds16(&Bt[(size_t)(bc * 128 + r0 + srow) * 1024 + kt + scol], &Bs[r0][0]);
        }
        __syncthreads();
#pragma unroll
        for (int kk = 0; kk < 64; kk += 32) {
            int ch = ((kk >> 3) + lk);
            bf16x8 af[4], bf[2];
#pragma unroll
            for (int m = 0; m < 4; ++m) af[m] = *(const bf16x8*)&As[m * 16 + lm][kk + lk * 8];
#pragma unroll
            for (int n = 0; n < 2; ++n)
                bf[n] = *(const bf16x8*)&Bs[w * 32 + n * 16 + lm][(ch ^ (lm & 7)) * 8];
#pragma unroll
            for (int m = 0; m < 4; ++m)
#pragma unroll
                for (int n = 0; n < 2; ++n)
                    acc[m][n] = __builtin_amdgcn_mfma_f32_16x16x32_bf16(af[m], bf[n], acc[m][n], 0, 0, 0);
        }
    }
#pragma unroll
    for (int m = 0; m < 4; ++m)
#pragma unroll
        for (int n = 0; n < 2; ++n) {
            int col = bc * 128 + w * 32 + n * 16 + lm;
            float bv = bias[col];
#pragma unroll
            for (int r = 0; r < 4; ++r) {
                int row = br * 64 + m * 16 + lk * 4 + r;
                C[(size_t)row * 1024 + col] = acc[m][n][r] + bv;
            }
        }
}

// ------------- flash attention (r14 2-buffer version, verbatim) -------------
__global__ __launch_bounds__(512) void flash_attn(const __bf16* __restrict__ Q,
                                                  const __bf16* __restrict__ Kb,
                                                  const __bf16* __restrict__ Vt,
                                                  __bf16* __restrict__ O) {
    __shared__ __bf16 Ks[2][64 * 64];
    __shared__ __bf16 Vs[2][64 * 64];
    int t = threadIdx.x, w = t >> 6, l = t & 63;
    int lm = l & 15, lk = l >> 4;
    int flat = blockIdx.x + 16 * blockIdx.y;
    int nf = (flat & 7) * 64 + (flat >> 3);
    int bh = nf >> 4, b = bh >> 4, h = bh & 15;
    int q0 = (nf & 15) * 128;

    bf16x8 qf[2];
#pragma unroll
    for (int kk = 0; kk < 2; ++kk)
        qf[kk] = *(const bf16x8*)&Q[(size_t)(b * SQ + q0 + w * 16 + lm) * DD + h * HS + kk * 32 + lk * 8];

    int r0 = t >> 3, c8 = t & 7;
    int chs = c8 ^ (r0 & 7);
    __bf16* ksl0 = &Ks[0][r0 * 64 + chs * 8];
    __bf16* vsl0 = &Vs[0][r0 * 64 + chs * 8];

    const __bf16* kp0 = Kb + (size_t)b * SK * DD + h * HS + (size_t)r0 * DD + c8 * 8;
    const __bf16* vp0 = Vt + (size_t)bh * HS * SK + (size_t)r0 * SK + c8 * 8;

    int o0 = lm * 64 + ((lk ^ (lm & 7)) * 8);
    int o1 = lm * 64 + (((4 + lk) ^ (lm & 7)) * 8);

    float4 kr0, vr0;
#define FA_LOAD()                                                                \
    kr0 = *(const float4*)kp0; vr0 = *(const float4*)vp0;                        \
    kp0 += (size_t)64 * DD; vp0 += 64;
#define FA_WRITE(BUF)                                                            \
    *(float4*)(ksl0 + (BUF) * 4096) = kr0;                                       \
    *(float4*)(vsl0 + (BUF) * 4096) = vr0;

    FA_LOAD();
    FA_WRITE(0);
    __syncthreads();

    bf16x8 ones;
#pragma unroll
    for (int j = 0; j < 8; ++j) ones[j] = (__bf16)1.0f;

    f32x4 o[4] = {};
    f32x4 o_s = {};

    for (int it = 0; it < 32; ++it) {
        int buf = it & 1;
        if (it + 1 < 32) { FA_LOAD(); }

        const __bf16* KsB = &Ks[buf][0];
        const __bf16* VsB = &Vs[buf][0];

        f32x4 st[4] = {};
        __builtin_amdgcn_s_setprio(1);
#pragma unroll
        for (int kk = 0; kk < 2; ++kk) {
#pragma unroll
            for (int n = 0; n < 4; ++n) {
                bf16x8 kf = *(const bf16x8*)&KsB[(kk ? o1 : o0) + n * 1024];
                st[n] = __builtin_amdgcn_mfma_f32_16x16x32_bf16(kf, qf[kk], st[n], 0, 0, 0);
            }
        }
        __builtin_amdgcn_s_setprio(0);

#pragma unroll
        for (int kk = 0; kk < 2; ++kk) {
            bf16x8 pa;
#pragma unroll
            for (int j = 0; j < 8; ++j)
                pa[j] = (__bf16)FEXP2(st[2 * kk + (j >> 2)][j & 3]);
            __builtin_amdgcn_s_setprio(1);
            o_s = __builtin_amdgcn_mfma_f32_16x16x32_bf16(pa, ones, o_s, 0, 0, 0);
#pragma unroll
            for (int dn = 0; dn < 4; ++dn) {
                bf16x8 vf = *(const bf16x8*)&VsB[(kk ? o1 : o0) + dn * 1024];
                o[dn] = __builtin_amdgcn_mfma_f32_16x16x32_bf16(pa, vf, o[dn], 0, 0, 0);
            }
            __builtin_amdgcn_s_setprio(0);
        }

        if (it + 1 < 32) { FA_WRITE(buf ^ 1); }
        __syncthreads();
    }

    f32x4 inv;
#pragma unroll
    for (int r = 0; r < 4; ++r) inv[r] = 1.f / o_s[r];
#pragma unroll
    for (int dn = 0; dn < 4; ++dn)
#pragma unroll
        for (int r = 0; r < 4; ++r) {
            int row = q0 + w * 16 + lk * 4 + r;
            int col = h * HS + dn * 16 + lm;
            O[(size_t)(b * SQ + row) * DD + col] = (__bf16)(o[dn][r] * inv[r]);
        }
}

extern "C" void kernel_launch(void* const* d_in, const int* in_sizes, int n_in,
                              void* d_out, int out_size, void* d_ws, size_t ws_size,
                              hipStream_t stream) {
    const float* inputs  = (const float*)d_in[0];
    const float* context = (const float*)d_in[1];
    const float* Wq = (const float*)d_in[2];
    const float* bq = (const float*)d_in[3];
    const float* Wk = (const float*)d_in[4];
    const float* bk = (const float*)d_in[5];
    const float* Wv = (const float*)d_in[6];
    const float* bv = (const float*)d_in[7];
    const float* Wo = (const float*)d_in[8];
    const float* bo = (const float*)d_in[9];
    float* out = (float*)d_out;

    char* ws = (char*)d_ws;
    const size_t SEG = (size_t)4096 * 1024 * sizeof(__bf16);  // 8 MB
    __bf16* attb = (__bf16*)(ws + 0 * SEG);   // attention output (bf16)
    __bf16* Wt   = (__bf16*)(ws + 2 * SEG);   // 4 x 1024x1024 bf16 (B-swizzled layout)
    __bf16* Qb   = (__bf16*)(ws + 3 * SEG);
    __bf16* Kbuf = (__bf16*)(ws + 4 * SEG);
    __bf16* Vtb  = (__bf16*)(ws + 5 * SEG);   // V transposed + sigma-permuted by gemm_qkv

    wtrans<<<dim3(32, 32, 4), dim3(32, 8), 0, stream>>>(Wq, Wk, Wv, Wo, Wt);

    gemm_qkv<<<dim3(16, 48), 256, 0, stream>>>(inputs, context, Wt, bq, bk, bv,
                                               Qb, Kbuf, Vtb, SCALE * LOG2E);

    flash_attn<<<dim3(16, 32), 512, 0, stream>>>(Qb, Kbuf, Vtb, attb);

    gemm_out64<<<dim3(8, 64), 256, 0, stream>>>(attb, Wt + (size_t)3 * DD * DD, bo, out);
}